// Round 12
// baseline (160.721 us; speedup 1.0000x reference)
//
#include <hip/hip_runtime.h>
#include <cstdint>
#include <cstddef>

typedef __bf16 bf16_t;
typedef __bf16 bf16x2 __attribute__((ext_vector_type(2)));
typedef __bf16 bf16x4 __attribute__((ext_vector_type(4)));
typedef __bf16 bf16x8 __attribute__((ext_vector_type(8)));
typedef float f32x4 __attribute__((ext_vector_type(4)));
typedef unsigned int u32x2 __attribute__((ext_vector_type(2)));

typedef __attribute__((address_space(1))) unsigned int gu32;
typedef __attribute__((address_space(3))) unsigned int lu32;

#define MFMA16(a, b, c) __builtin_amdgcn_mfma_f32_16x16x32_bf16((a), (b), (c), 0, 0, 0)

__device__ __forceinline__ void gload_lds16(const void* g, void* l) {
    __builtin_amdgcn_global_load_lds((gu32*)const_cast<void*>(g), (lu32*)l, 16, 0, 0);
}

// ---------------------------------------------------------------------------
// fp32 -> bf16 bulk convert. z: 0 = x (4M el), 1..3 = Wq/Wk/Wv (1M el each).
// ---------------------------------------------------------------------------
__global__ __launch_bounds__(256) void cvt_bf16(
    const float* __restrict__ x, const float* __restrict__ Wq,
    const float* __restrict__ Wk, const float* __restrict__ Wv,
    bf16_t* __restrict__ xb, bf16_t* __restrict__ Wqb,
    bf16_t* __restrict__ Wkb, bf16_t* __restrict__ Wvb)
{
    const int z = blockIdx.z;
    const float* src = (z == 0) ? x : (z == 1) ? Wq : (z == 2) ? Wk : Wv;
    bf16_t* dst      = (z == 0) ? xb : (z == 1) ? Wqb : (z == 2) ? Wkb : Wvb;
    const int n = (z == 0) ? 4096 * 1024 : 1024 * 1024;
    const int stride = gridDim.x * blockDim.x * 4;
    for (int i = (blockIdx.x * blockDim.x + threadIdx.x) * 4; i < n; i += stride) {
        const float4 f = *(const float4*)(src + i);
        bf16x4 o; o[0] = (bf16_t)f.x; o[1] = (bf16_t)f.y; o[2] = (bf16_t)f.z; o[3] = (bf16_t)f.w;
        *(bf16x4*)(dst + i) = o;
    }
}

// ---------------------------------------------------------------------------
// bf16 QKV GEMM, 8-wave blocks, 128x128 tile, BK=32, dbuf LDS, 1 barrier/iter.
// z==0 (Q) is PRESCALED by 0.125*log2(e): attn computes 2^x with the bare
// hardware v_exp_f32. z==2 (V) writes TRANSPOSED VT[b][h][w][s] AND
// per-block Vsum partials. grid (32,8,3), 512 threads.
// ---------------------------------------------------------------------------
__global__ __launch_bounds__(512) void qkv_gemm_bf16(
    const bf16_t* __restrict__ xb,
    const bf16_t* __restrict__ W0b, const float* __restrict__ b0,
    const bf16_t* __restrict__ W1b, const float* __restrict__ b1,
    const bf16_t* __restrict__ W2b, const float* __restrict__ b2,
    bf16_t* __restrict__ Qo, bf16_t* __restrict__ Ko, bf16_t* __restrict__ VTo,
    float* __restrict__ Vp)
{
    const int z = blockIdx.z;
    const bf16_t* Wm = (z == 0) ? W0b : (z == 1) ? W1b : W2b;
    const float* bia = (z == 0) ? b0 : (z == 1) ? b1 : b2;

    __shared__ bf16_t As[2][128 * 32];
    __shared__ bf16_t Bs[2][128 * 32];

    const int tid  = threadIdx.x;
    const int lane = tid & 63;
    const int wv   = tid >> 6;       // 0..7
    const int quad = lane >> 4;
    const int l16  = lane & 15;
    const int wm   = wv >> 1;        // 0..3 : 32-row quarter
    const int wn   = wv & 1;         // 0..1 : 64-col half
    const int m0   = blockIdx.x * 128;
    const int n0   = blockIdx.y * 128;

    const int rs = tid >> 2;                              // row 0..127
    const int gs = ((tid & 3) ^ ((rs >> 1) & 3)) * 8;     // swizzled col (el)
    const int fp = (quad ^ ((l16 >> 1) & 3)) * 8;         // fragment swizzle

    f32x4 acc[2][4];
    for (int i = 0; i < 2; i++)
        for (int j = 0; j < 4; j++) acc[i][j] = (f32x4)0.0f;

    gload_lds16(xb + (size_t)(m0 + rs) * 1024 + gs, &As[0][(wv * 64) * 8]);
    gload_lds16(Wm + (size_t)(n0 + rs) * 1024 + gs, &Bs[0][(wv * 64) * 8]);

#pragma unroll 2
    for (int kt = 0; kt < 32; kt++) {
        const int cur = kt & 1, nxt = cur ^ 1;
        __syncthreads();
        if (kt < 31) {
            const int kp = (kt + 1) * 32;
            gload_lds16(xb + (size_t)(m0 + rs) * 1024 + kp + gs, &As[nxt][(wv * 64) * 8]);
            gload_lds16(Wm + (size_t)(n0 + rs) * 1024 + kp + gs, &Bs[nxt][(wv * 64) * 8]);
        }
        bf16x8 af[2], bfr[4];
        for (int mt = 0; mt < 2; mt++)
            af[mt] = *(const bf16x8*)&As[cur][(wm * 32 + mt * 16 + l16) * 32 + fp];
        for (int nt = 0; nt < 4; nt++)
            bfr[nt] = *(const bf16x8*)&Bs[cur][(wn * 64 + nt * 16 + l16) * 32 + fp];
        for (int mt = 0; mt < 2; mt++)
            for (int nt = 0; nt < 4; nt++)
                acc[mt][nt] = MFMA16(af[mt], bfr[nt], acc[mt][nt]);
    }

    float bv[4];
    for (int nt = 0; nt < 4; nt++)
        bv[nt] = bia[n0 + wn * 64 + nt * 16 + l16];

    if (z < 2) {
        bf16_t* out = (z == 0) ? Qo : Ko;
        // 0.125 (softmax scale) * log2(e): attn uses raw v_exp_f32 (2^x)
        const float scl = (z == 0) ? 0.18033688011112042f : 1.0f;
        for (int mt = 0; mt < 2; mt++) {
            const int mrow = m0 + wm * 32 + mt * 16 + quad * 4;
            for (int nt = 0; nt < 4; nt++) {
                const int n = n0 + wn * 64 + nt * 16 + l16;
                for (int r = 0; r < 4; r++)
                    out[(size_t)(mrow + r) * 1024 + n] = (bf16_t)((acc[mt][nt][r] + bv[nt]) * scl);
            }
        }
    } else {
        const int h = blockIdx.y * 2 + wn;
        float psum[4] = {0.f, 0.f, 0.f, 0.f};
        for (int mt = 0; mt < 2; mt++) {
            const int sg = m0 + wm * 32 + mt * 16 + quad * 4;
            const int bb = sg >> 11;
            const int s  = sg & 2047;
            for (int nt = 0; nt < 4; nt++) {
                const int w = nt * 16 + l16;
                bf16x4 pk;
                for (int r = 0; r < 4; r++) {
                    pk[r] = (bf16_t)(acc[mt][nt][r] + bv[nt]);
                    psum[nt] += (float)pk[r];
                }
                *(bf16x4*)(VTo + ((size_t)((bb * 16 + h) * 64 + w)) * 2048 + s) = pk;
            }
        }
        for (int nt = 0; nt < 4; nt++) {
            psum[nt] += __shfl_xor(psum[nt], 16, 64);
            psum[nt] += __shfl_xor(psum[nt], 32, 64);
        }
        float* red = (float*)&As[0][0];
        if (quad == 0)
            for (int nt = 0; nt < 4; nt++)
                red[(wv * 4 + nt) * 16 + l16] = psum[nt];
        __syncthreads();
        if (wm == 0 && quad == 0) {
            const int bb = m0 >> 11;
            const int j  = blockIdx.x & 15;
            for (int nt = 0; nt < 4; nt++) {
                float s4 = ((red[((wn + 0) * 4 + nt) * 16 + l16]
                           + red[((wn + 2) * 4 + nt) * 16 + l16])
                           + red[((wn + 4) * 4 + nt) * 16 + l16])
                           + red[((wn + 6) * 4 + nt) * 16 + l16];
                Vp[((size_t)((bb * 16 + h) * 64 + nt * 16 + l16)) * 16 + j] = s4;
            }
        }
    }
}

// ---------------------------------------------------------------------------
// Single-pass double-softmax attention, v16 = v12 (r8-verified best, 155.7)
// with Q DIRECT-TO-REGISTER: Q was staged through LDS but read exactly once
// into registers (aq). Load it global->reg instead (logical chunk quad*8 /
// 32+quad*8 — the LDS swizzle and its inverse cancel; bf16 values
// bit-identical). Deletes the Q staging round-trip (2 gload_lds + 4 LDS
// reads/thread + first-barrier dependency), LDS 48->32 KB. Epilogue reduce
// two-phase to fit 32 KB (v13's epilogue, correctness-verified in r9).
// NO remap (v15 null), NO paired staging (v14 null), NO reg-V (v13 regress).
// grid (16,16,2), block 512, LDS 32 KB.
// ---------------------------------------------------------------------------
__global__ __launch_bounds__(512, 4) void attn(
    const bf16_t* __restrict__ Qg, const bf16_t* __restrict__ Kg,
    const bf16_t* __restrict__ VTg, const float* __restrict__ Vp,
    float* __restrict__ out)
{
    const int qt = blockIdx.x;
    const int h  = blockIdx.y;
    const int b  = blockIdx.z;

    const int tid  = threadIdx.x;
    const int wv   = tid >> 6;       // 0..7
    const int lane = tid & 63;
    const int quad = lane >> 4;
    const int l16  = lane & 15;
    const int qg   = wv >> 1;        // 0..3 : 32-q group
    const int sh   = wv & 1;         // 0..1 : 32-s half of each tile

    const size_t base  = ((size_t)b * 2048) * 1024 + (size_t)h * 64;   // Q/K
    const size_t vbase = ((size_t)(b * 16 + h) * 64) * 2048;           // VT
    const int q0 = qt * 128;

    // 32 KB: Ks0[8K] | Ks1[8K] @8192 | Vs0[8K] @16384 | Vs1[8K] @24576
    __shared__ __align__(16) unsigned char smem[32768];

    // Q fragments straight from global (read-once; logical chunks quad, 4+quad)
    const int qr0 = qg * 32 + l16;         // qs=0 row
    const int qr1 = qg * 32 + 16 + l16;    // qs=1 row
    bf16x8 aq[2][2];
    aq[0][0] = *(const bf16x8*)(Qg + base + (size_t)(q0 + qr0) * 1024 + quad * 8);
    aq[0][1] = *(const bf16x8*)(Qg + base + (size_t)(q0 + qr0) * 1024 + 32 + quad * 8);
    aq[1][0] = *(const bf16x8*)(Qg + base + (size_t)(q0 + qr1) * 1024 + quad * 8);
    aq[1][1] = *(const bf16x8*)(Qg + base + (size_t)(q0 + qr1) * 1024 + 32 + quad * 8);

    // K/V staging: 512 chunks, 1 per thread (VT rows are w, stride 2048)
    const int rk = tid >> 3;
    const int gk = ((tid & 7) ^ (rk & 7)) * 8;
    gload_lds16(Kg + base + (size_t)rk * 1024 + gk,
                (bf16_t*)(smem) + (wv * 64) * 8);
    gload_lds16(VTg + vbase + (size_t)rk * 2048 + gk,
                (bf16_t*)(smem + 16384) + (wv * 64) * 8);

    const int fs0 = ((0 ^ quad) ^ (l16 & 7)) * 8;   // 16B chunk cc = quad
    const int fs1 = ((4 ^ quad) ^ (l16 & 7)) * 8;   // 16B chunk cc = 4+quad
    const int fsA = sh ? fs1 : fs0;                 // this wave's s-half slice

    f32x4 oa[2][4], l1acc[2];
    for (int qs = 0; qs < 2; qs++) {
        for (int nt = 0; nt < 4; nt++) oa[qs][nt] = (f32x4)0.0f;
        l1acc[qs] = (f32x4)0.0f;
    }

    bf16x8 ones;
    for (int j = 0; j < 8; j++) ones[j] = (bf16_t)1.0f;

    __syncthreads();   // K0/V0 landed

    bf16x8 af[2];    // P A-frags of tile kt (in-register)
    bf16x8 bvf[4];   // V-frags of tile kt (this wave's s-half)

    // exp2 (bare v_exp_f32) + quad-exchange: sa -> af (pure VALU + permlane)
    #define EXCHANGE_P(PS_SA)                                                   \
        for (int qs = 0; qs < 2; qs++) {                                        \
            union { bf16x2 h; unsigned int u; } t00, t01, t10, t11;             \
            t00.h[0] = (bf16_t)__builtin_amdgcn_exp2f(PS_SA[0][qs][0]);         \
            t00.h[1] = (bf16_t)__builtin_amdgcn_exp2f(PS_SA[0][qs][1]);         \
            t01.h[0] = (bf16_t)__builtin_amdgcn_exp2f(PS_SA[0][qs][2]);         \
            t01.h[1] = (bf16_t)__builtin_amdgcn_exp2f(PS_SA[0][qs][3]);         \
            t10.h[0] = (bf16_t)__builtin_amdgcn_exp2f(PS_SA[1][qs][0]);         \
            t10.h[1] = (bf16_t)__builtin_amdgcn_exp2f(PS_SA[1][qs][1]);         \
            t11.h[0] = (bf16_t)__builtin_amdgcn_exp2f(PS_SA[1][qs][2]);         \
            t11.h[1] = (bf16_t)__builtin_amdgcn_exp2f(PS_SA[1][qs][3]);         \
            u32x2 p0 = __builtin_amdgcn_permlane32_swap(t00.u, t10.u, false, false); \
            u32x2 e0 = __builtin_amdgcn_permlane16_swap(p0[0], p0[1], false, false); \
            u32x2 p1 = __builtin_amdgcn_permlane32_swap(t01.u, t11.u, false, false); \
            u32x2 e1 = __builtin_amdgcn_permlane16_swap(p1[0], p1[1], false, false); \
            union { unsigned int u[4]; bf16x8 h; } w;                           \
            w.u[0] = e0[0]; w.u[1] = e1[0]; w.u[2] = e0[1]; w.u[3] = e1[1];     \
            af[qs] = w.h;                                                       \
        }

    // ---- iter 0 (peeled): QK + exp/exchange + V0 frags; no PV yet ----
    {
        const bf16_t* Ks0 = (const bf16_t*)(smem);
        const bf16_t* Vs0 = (const bf16_t*)(smem + 16384);
        gload_lds16(Kg + base + (size_t)(64 + rk) * 1024 + gk,
                    (bf16_t*)(smem + 8192) + (wv * 64) * 8);
        gload_lds16(VTg + vbase + (size_t)rk * 2048 + 64 + gk,
                    (bf16_t*)(smem + 24576) + (wv * 64) * 8);

        f32x4 sa[2][2];   // [st][qs]
        for (int st = 0; st < 2; st++)
            for (int qs = 0; qs < 2; qs++) sa[st][qs] = (f32x4)0.0f;
        for (int st = 0; st < 2; st++) {
            const int srow = (sh * 32 + st * 16 + l16) * 64;
            bf16x8 kb0 = *(const bf16x8*)&Ks0[srow + fs0];
            bf16x8 kb1 = *(const bf16x8*)&Ks0[srow + fs1];
            for (int qs = 0; qs < 2; qs++) {
                sa[st][qs] = MFMA16(kb0, aq[qs][0], sa[st][qs]);
                sa[st][qs] = MFMA16(kb1, aq[qs][1], sa[st][qs]);
            }
        }
        EXCHANGE_P(sa)
        for (int nt = 0; nt < 4; nt++)
            bvf[nt] = *(const bf16x8*)&Vs0[(nt * 16 + l16) * 64 + fsA];
    }

    // ---- main loop kt = 1..31: QK(kt) + PV(kt-1); exchange(kt) -> af ----
#pragma unroll 2
    for (int kt = 1; kt < 32; kt++) {
        const int cur = kt & 1, prv = cur ^ 1;
        const bf16_t* KsC = (const bf16_t*)(smem + cur * 8192);
        const bf16_t* VsC = (const bf16_t*)(smem + 16384 + cur * 8192);
        __syncthreads();   // K/V tile kt landed

        if (kt < 31) {
            gload_lds16(Kg + base + (size_t)((kt + 1) * 64 + rk) * 1024 + gk,
                        (bf16_t*)(smem + prv * 8192) + (wv * 64) * 8);
            gload_lds16(VTg + vbase + (size_t)rk * 2048 + (kt + 1) * 64 + gk,
                        (bf16_t*)(smem + 16384 + prv * 8192) + (wv * 64) * 8);
        }

        // QK(kt): S^T chunk [32s x 32q]; each K-frag feeds both q-subtiles
        f32x4 sa[2][2];
        for (int st = 0; st < 2; st++)
            for (int qs = 0; qs < 2; qs++) sa[st][qs] = (f32x4)0.0f;
        __builtin_amdgcn_s_setprio(1);
        for (int st = 0; st < 2; st++) {
            const int srow = (sh * 32 + st * 16 + l16) * 64;
            bf16x8 kb0 = *(const bf16x8*)&KsC[srow + fs0];
            bf16x8 kb1 = *(const bf16x8*)&KsC[srow + fs1];
            for (int qs = 0; qs < 2; qs++) {
                sa[st][qs] = MFMA16(kb0, aq[qs][0], sa[st][qs]);
                sa[st][qs] = MFMA16(kb1, aq[qs][1], sa[st][qs]);
            }
        }

        // PV(kt-1): U += E1 @ V ; l1 += E1 @ ones  (s-partial, this sh only)
        l1acc[0] = MFMA16(af[0], ones, l1acc[0]);
        l1acc[1] = MFMA16(af[1], ones, l1acc[1]);
        for (int nt = 0; nt < 4; nt++) {
            oa[0][nt] = MFMA16(af[0], bvf[nt], oa[0][nt]);
            oa[1][nt] = MFMA16(af[1], bvf[nt], oa[1][nt]);
        }
        __builtin_amdgcn_s_setprio(0);

        // V(kt) frags for next iteration (Vs[cur] stable this iter)
        for (int nt = 0; nt < 4; nt++)
            bvf[nt] = *(const bf16x8*)&VsC[(nt * 16 + l16) * 64 + fsA];

        // exp2(kt) + quad-exchange -> af, under the PV MFMA drain
        EXCHANGE_P(sa)
    }

    // ---- drain: PV(31) from held af/bvf ----
    {
        l1acc[0] = MFMA16(af[0], ones, l1acc[0]);
        l1acc[1] = MFMA16(af[1], ones, l1acc[1]);
        for (int nt = 0; nt < 4; nt++) {
            oa[0][nt] = MFMA16(af[0], bvf[nt], oa[0][nt]);
            oa[1][nt] = MFMA16(af[1], bvf[nt], oa[1][nt]);
        }
    }

    // ---- pair-reduce (sh=1 -> sh=0), two phases to fit 32 KB LDS ----
    __syncthreads();   // all iter-31 K/V reads done before overlay writes
    f32x4* R4 = (f32x4*)smem;                 // 2048 slots = 32 KB (exact)
    const int bi = qg * 64 + lane;
    if (sh == 1) {
        for (int qs = 0; qs < 2; qs++)
            for (int nt = 0; nt < 4; nt++)
                R4[bi * 8 + ((qs * 4 + nt) ^ (lane & 7))] = oa[qs][nt];
    }
    __syncthreads();
    if (sh == 0) {
        for (int qs = 0; qs < 2; qs++)
            for (int nt = 0; nt < 4; nt++)
                oa[qs][nt] += R4[bi * 8 + ((qs * 4 + nt) ^ (lane & 7))];
    }
    __syncthreads();
    if (sh == 1) {                            // phase B: l1 (8 KB region)
        R4[bi * 2 + 0] = l1acc[0];
        R4[bi * 2 + 1] = l1acc[1];
    }
    __syncthreads();
    if (sh == 0) {
        l1acc[0] += R4[bi * 2 + 0];
        l1acc[1] += R4[bi * 2 + 1];

        float invq[2][4];
        for (int qs = 0; qs < 2; qs++)
            for (int r = 0; r < 4; r++) invq[qs][r] = 1.0f / l1acc[qs][r];

        // Vsum[w] from Vpart: each quad sums 4 of the 16 partials, butterfly
        float vs[4];
        const size_t vprow = (size_t)(b * 16 + h) * 64;
        for (int nt = 0; nt < 4; nt++) {
            const f32x4 p4 = *(const f32x4*)&Vp[(vprow + nt * 16 + l16) * 16 + quad * 4];
            float t = (p4[0] + p4[1]) + (p4[2] + p4[3]);
            t += __shfl_xor(t, 16, 64);
            t += __shfl_xor(t, 32, 64);
            vs[nt] = t;
        }

        const float inv_denom = 1.0f / 2049.0f;
        for (int qs = 0; qs < 2; qs++)
            for (int nt = 0; nt < 4; nt++)
                for (int r = 0; r < 4; r++) {
                    const int srow = q0 + qg * 32 + qs * 16 + quad * 4 + r;
                    out[((size_t)b * 2048 + srow) * 1024 + (size_t)h * 64 + nt * 16 + l16] =
                        (vs[nt] + oa[qs][nt][r] * invq[qs][r]) * inv_denom;
                }
    }
    #undef EXCHANGE_P
}

// ---------------------------------------------------------------------------
extern "C" void kernel_launch(void* const* d_in, const int* in_sizes, int n_in,
                              void* d_out, int out_size, void* d_ws, size_t ws_size,
                              hipStream_t stream) {
    const float* x  = (const float*)d_in[0];
    const float* Wq = (const float*)d_in[1];
    const float* bq = (const float*)d_in[2];
    const float* Wk = (const float*)d_in[3];
    const float* bk = (const float*)d_in[4];
    const float* Wv = (const float*)d_in[5];
    const float* bv = (const float*)d_in[6];

    // Q/K/VT bf16 workspace (24 MB) + Vpart f32 partials (128 KB at +24 MB)
    bf16_t* Qw  = (bf16_t*)d_ws;
    bf16_t* Kw  = Qw + (size_t)4096 * 1024;
    bf16_t* VTw = Kw + (size_t)4096 * 1024;
    float*  Vp  = (float*)(VTw + (size_t)4096 * 1024);   // 2048 x 16 f32

    // bf16 input staging lives in d_out (16 MB; attn overwrites it last)
    bf16_t* xb  = (bf16_t*)d_out;
    bf16_t* Wqb = xb + (size_t)4096 * 1024;
    bf16_t* Wkb = Wqb + (size_t)1024 * 1024;
    bf16_t* Wvb = Wkb + (size_t)1024 * 1024;

    cvt_bf16<<<dim3(1024, 1, 4), 256, 0, stream>>>(x, Wq, Wk, Wv, xb, Wqb, Wkb, Wvb);
    qkv_gemm_bf16<<<dim3(32, 8, 3), 512, 0, stream>>>(
        xb, Wqb, bq, Wkb, bk, Wvb, bv, Qw, Kw, VTw, Vp);
    attn<<<dim3(16, 16, 2), 512, 0, stream>>>(Qw, Kw, VTw, Vp, (float*)d_out);
}

// Round 13
// 153.724 us; speedup vs baseline: 1.0455x; 1.0455x over previous
//
#include <hip/hip_runtime.h>
#include <cstdint>
#include <cstddef>

typedef __bf16 bf16_t;
typedef __bf16 bf16x2 __attribute__((ext_vector_type(2)));
typedef __bf16 bf16x4 __attribute__((ext_vector_type(4)));
typedef __bf16 bf16x8 __attribute__((ext_vector_type(8)));
typedef float f32x4 __attribute__((ext_vector_type(4)));
typedef unsigned int u32x2 __attribute__((ext_vector_type(2)));

typedef __attribute__((address_space(1))) unsigned int gu32;
typedef __attribute__((address_space(3))) unsigned int lu32;

#define MFMA16(a, b, c) __builtin_amdgcn_mfma_f32_16x16x32_bf16((a), (b), (c), 0, 0, 0)

__device__ __forceinline__ void gload_lds16(const void* g, void* l) {
    __builtin_amdgcn_global_load_lds((gu32*)const_cast<void*>(g), (lu32*)l, 16, 0, 0);
}

// ---------------------------------------------------------------------------
// fp32 -> bf16 bulk convert. z: 0 = x (4M el), 1..3 = Wq/Wk/Wv (1M el each).
// ---------------------------------------------------------------------------
__global__ __launch_bounds__(256) void cvt_bf16(
    const float* __restrict__ x, const float* __restrict__ Wq,
    const float* __restrict__ Wk, const float* __restrict__ Wv,
    bf16_t* __restrict__ xb, bf16_t* __restrict__ Wqb,
    bf16_t* __restrict__ Wkb, bf16_t* __restrict__ Wvb)
{
    const int z = blockIdx.z;
    const float* src = (z == 0) ? x : (z == 1) ? Wq : (z == 2) ? Wk : Wv;
    bf16_t* dst      = (z == 0) ? xb : (z == 1) ? Wqb : (z == 2) ? Wkb : Wvb;
    const int n = (z == 0) ? 4096 * 1024 : 1024 * 1024;
    const int stride = gridDim.x * blockDim.x * 4;
    for (int i = (blockIdx.x * blockDim.x + threadIdx.x) * 4; i < n; i += stride) {
        const float4 f = *(const float4*)(src + i);
        bf16x4 o; o[0] = (bf16_t)f.x; o[1] = (bf16_t)f.y; o[2] = (bf16_t)f.z; o[3] = (bf16_t)f.w;
        *(bf16x4*)(dst + i) = o;
    }
}

// ---------------------------------------------------------------------------
// bf16 QKV GEMM, 8-wave blocks, 128x128 tile, BK=32, dbuf LDS, 1 barrier/iter.
// (Prior session: 4-wave 64x64-wave variant measured SLOWER — gemm is
// latency-bound at 12 waves/CU; keep 24 waves/CU. Do not re-try.)
// z==0 (Q) is PRESCALED by 0.125*log2(e): attn computes 2^x with the bare
// hardware v_exp_f32. z==2 (V) writes TRANSPOSED VT[b][h][w][s] AND
// per-block Vsum partials. grid (32,8,3), 512 threads.
// ---------------------------------------------------------------------------
__global__ __launch_bounds__(512) void qkv_gemm_bf16(
    const bf16_t* __restrict__ xb,
    const bf16_t* __restrict__ W0b, const float* __restrict__ b0,
    const bf16_t* __restrict__ W1b, const float* __restrict__ b1,
    const bf16_t* __restrict__ W2b, const float* __restrict__ b2,
    bf16_t* __restrict__ Qo, bf16_t* __restrict__ Ko, bf16_t* __restrict__ VTo,
    float* __restrict__ Vp)
{
    const int z = blockIdx.z;
    const bf16_t* Wm = (z == 0) ? W0b : (z == 1) ? W1b : W2b;
    const float* bia = (z == 0) ? b0 : (z == 1) ? b1 : b2;

    __shared__ bf16_t As[2][128 * 32];
    __shared__ bf16_t Bs[2][128 * 32];

    const int tid  = threadIdx.x;
    const int lane = tid & 63;
    const int wv   = tid >> 6;       // 0..7
    const int quad = lane >> 4;
    const int l16  = lane & 15;
    const int wm   = wv >> 1;        // 0..3 : 32-row quarter
    const int wn   = wv & 1;         // 0..1 : 64-col half
    const int m0   = blockIdx.x * 128;
    const int n0   = blockIdx.y * 128;

    const int rs = tid >> 2;                              // row 0..127
    const int gs = ((tid & 3) ^ ((rs >> 1) & 3)) * 8;     // swizzled col (el)
    const int fp = (quad ^ ((l16 >> 1) & 3)) * 8;         // fragment swizzle

    f32x4 acc[2][4];
    for (int i = 0; i < 2; i++)
        for (int j = 0; j < 4; j++) acc[i][j] = (f32x4)0.0f;

    gload_lds16(xb + (size_t)(m0 + rs) * 1024 + gs, &As[0][(wv * 64) * 8]);
    gload_lds16(Wm + (size_t)(n0 + rs) * 1024 + gs, &Bs[0][(wv * 64) * 8]);

#pragma unroll 2
    for (int kt = 0; kt < 32; kt++) {
        const int cur = kt & 1, nxt = cur ^ 1;
        __syncthreads();
        if (kt < 31) {
            const int kp = (kt + 1) * 32;
            gload_lds16(xb + (size_t)(m0 + rs) * 1024 + kp + gs, &As[nxt][(wv * 64) * 8]);
            gload_lds16(Wm + (size_t)(n0 + rs) * 1024 + kp + gs, &Bs[nxt][(wv * 64) * 8]);
        }
        bf16x8 af[2], bfr[4];
        for (int mt = 0; mt < 2; mt++)
            af[mt] = *(const bf16x8*)&As[cur][(wm * 32 + mt * 16 + l16) * 32 + fp];
        for (int nt = 0; nt < 4; nt++)
            bfr[nt] = *(const bf16x8*)&Bs[cur][(wn * 64 + nt * 16 + l16) * 32 + fp];
        for (int mt = 0; mt < 2; mt++)
            for (int nt = 0; nt < 4; nt++)
                acc[mt][nt] = MFMA16(af[mt], bfr[nt], acc[mt][nt]);
    }

    float bv[4];
    for (int nt = 0; nt < 4; nt++)
        bv[nt] = bia[n0 + wn * 64 + nt * 16 + l16];

    if (z < 2) {
        bf16_t* out = (z == 0) ? Qo : Ko;
        // 0.125 (softmax scale) * log2(e): attn uses raw v_exp_f32 (2^x)
        const float scl = (z == 0) ? 0.18033688011112042f : 1.0f;
        for (int mt = 0; mt < 2; mt++) {
            const int mrow = m0 + wm * 32 + mt * 16 + quad * 4;
            for (int nt = 0; nt < 4; nt++) {
                const int n = n0 + wn * 64 + nt * 16 + l16;
                for (int r = 0; r < 4; r++)
                    out[(size_t)(mrow + r) * 1024 + n] = (bf16_t)((acc[mt][nt][r] + bv[nt]) * scl);
            }
        }
    } else {
        const int h = blockIdx.y * 2 + wn;
        float psum[4] = {0.f, 0.f, 0.f, 0.f};
        for (int mt = 0; mt < 2; mt++) {
            const int sg = m0 + wm * 32 + mt * 16 + quad * 4;
            const int bb = sg >> 11;
            const int s  = sg & 2047;
            for (int nt = 0; nt < 4; nt++) {
                const int w = nt * 16 + l16;
                bf16x4 pk;
                for (int r = 0; r < 4; r++) {
                    pk[r] = (bf16_t)(acc[mt][nt][r] + bv[nt]);
                    psum[nt] += (float)pk[r];
                }
                *(bf16x4*)(VTo + ((size_t)((bb * 16 + h) * 64 + w)) * 2048 + s) = pk;
            }
        }
        for (int nt = 0; nt < 4; nt++) {
            psum[nt] += __shfl_xor(psum[nt], 16, 64);
            psum[nt] += __shfl_xor(psum[nt], 32, 64);
        }
        float* red = (float*)&As[0][0];
        if (quad == 0)
            for (int nt = 0; nt < 4; nt++)
                red[(wv * 4 + nt) * 16 + l16] = psum[nt];
        __syncthreads();
        if (wm == 0 && quad == 0) {
            const int bb = m0 >> 11;
            const int j  = blockIdx.x & 15;
            for (int nt = 0; nt < 4; nt++) {
                float s4 = ((red[((wn + 0) * 4 + nt) * 16 + l16]
                           + red[((wn + 2) * 4 + nt) * 16 + l16])
                           + red[((wn + 4) * 4 + nt) * 16 + l16])
                           + red[((wn + 6) * 4 + nt) * 16 + l16];
                Vp[((size_t)((bb * 16 + h) * 64 + nt * 16 + l16)) * 16 + j] = s4;
            }
        }
    }
}

// ---------------------------------------------------------------------------
// Single-pass double-softmax attention, v17 == v12 (r8-verified session best,
// 155.7 µs total). FINAL REVERT: every structural alternative was measured
// and lost — v9 256q-tile (occupancy loss, 63µs), v13 register-V (L2 latency
// exposure, 75µs), v14 paired staging (null), v15 XCD remap (null), v16
// Q-direct-to-reg (uncoalesced Q loads, +5µs). Kernel is latency-bound at
// grid-structural occupancy (512 blocks = 2/CU); LDS ~most-loaded pipe with
// irreducible traffic; setprio + bare-v_exp_f32 exp2 + in-register P
// (permlane quad-exchange) + hoisted Vsum are the accumulated wins.
// grid (16,16,2), block 512, LDS 48 KB.
// ---------------------------------------------------------------------------
__global__ __launch_bounds__(512, 4) void attn(
    const bf16_t* __restrict__ Qg, const bf16_t* __restrict__ Kg,
    const bf16_t* __restrict__ VTg, const float* __restrict__ Vp,
    float* __restrict__ out)
{
    const int qt = blockIdx.x;
    const int h  = blockIdx.y;
    const int b  = blockIdx.z;

    const int tid  = threadIdx.x;
    const int wv   = tid >> 6;       // 0..7
    const int lane = tid & 63;
    const int quad = lane >> 4;
    const int l16  = lane & 15;
    const int qg   = wv >> 1;        // 0..3 : 32-q group
    const int sh   = wv & 1;         // 0..1 : 32-s half of each tile

    const size_t base  = ((size_t)b * 2048) * 1024 + (size_t)h * 64;   // Q/K
    const size_t vbase = ((size_t)(b * 16 + h) * 64) * 2048;           // VT
    const int q0 = qt * 128;

    // 48 KB: Qs[16K] | Ks0[8K] | Ks1[8K] | Vs0[8K] | Vs1[8K]
    __shared__ __align__(16) unsigned char smem[49152];
    bf16_t* Qs = (bf16_t*)smem;

    // Q staging into Qs: 1024 chunks, 2 per thread
    {
        const int c0 = tid, c1 = 512 + tid;
        const int r0 = c0 >> 3, g0 = ((c0 & 7) ^ (r0 & 7)) * 8;
        const int r1 = c1 >> 3, g1 = ((c1 & 7) ^ (r1 & 7)) * 8;
        gload_lds16(Qg + base + (size_t)(q0 + r0) * 1024 + g0, Qs + (wv * 64) * 8);
        gload_lds16(Qg + base + (size_t)(q0 + r1) * 1024 + g1, Qs + (512 + wv * 64) * 8);
    }
    // K/V staging: 512 chunks, 1 per thread (VT rows are w, stride 2048)
    const int rk = tid >> 3;
    const int gk = ((tid & 7) ^ (rk & 7)) * 8;
    gload_lds16(Kg + base + (size_t)rk * 1024 + gk,
                (bf16_t*)(smem + 16384) + (wv * 64) * 8);
    gload_lds16(VTg + vbase + (size_t)rk * 2048 + gk,
                (bf16_t*)(smem + 32768) + (wv * 64) * 8);

    const int fs0 = ((0 ^ quad) ^ (l16 & 7)) * 8;   // 16B chunk cc = quad
    const int fs1 = ((4 ^ quad) ^ (l16 & 7)) * 8;   // 16B chunk cc = 4+quad
    const int fsA = sh ? fs1 : fs0;                 // this wave's s-half slice

    const int qr0 = qg * 32 + l16;         // qs=0 row
    const int qr1 = qg * 32 + 16 + l16;    // qs=1 row

    f32x4 oa[2][4], l1acc[2];
    for (int qs = 0; qs < 2; qs++) {
        for (int nt = 0; nt < 4; nt++) oa[qs][nt] = (f32x4)0.0f;
        l1acc[qs] = (f32x4)0.0f;
    }

    bf16x8 ones;
    for (int j = 0; j < 8; j++) ones[j] = (bf16_t)1.0f;

    __syncthreads();   // Q/K0/V0 landed

    // hoist Q fragments: aq[qs][kh]
    bf16x8 aq[2][2];
    aq[0][0] = *(const bf16x8*)&Qs[qr0 * 64 + fs0];
    aq[0][1] = *(const bf16x8*)&Qs[qr0 * 64 + fs1];
    aq[1][0] = *(const bf16x8*)&Qs[qr1 * 64 + fs0];
    aq[1][1] = *(const bf16x8*)&Qs[qr1 * 64 + fs1];

    bf16x8 af[2];    // P A-frags of tile kt (in-register)
    bf16x8 bvf[4];   // V-frags of tile kt (this wave's s-half)

    // exp2 (bare v_exp_f32) + quad-exchange: sa -> af (pure VALU + permlane)
    #define EXCHANGE_P(PS_SA)                                                   \
        for (int qs = 0; qs < 2; qs++) {                                        \
            union { bf16x2 h; unsigned int u; } t00, t01, t10, t11;             \
            t00.h[0] = (bf16_t)__builtin_amdgcn_exp2f(PS_SA[0][qs][0]);         \
            t00.h[1] = (bf16_t)__builtin_amdgcn_exp2f(PS_SA[0][qs][1]);         \
            t01.h[0] = (bf16_t)__builtin_amdgcn_exp2f(PS_SA[0][qs][2]);         \
            t01.h[1] = (bf16_t)__builtin_amdgcn_exp2f(PS_SA[0][qs][3]);         \
            t10.h[0] = (bf16_t)__builtin_amdgcn_exp2f(PS_SA[1][qs][0]);         \
            t10.h[1] = (bf16_t)__builtin_amdgcn_exp2f(PS_SA[1][qs][1]);         \
            t11.h[0] = (bf16_t)__builtin_amdgcn_exp2f(PS_SA[1][qs][2]);         \
            t11.h[1] = (bf16_t)__builtin_amdgcn_exp2f(PS_SA[1][qs][3]);         \
            u32x2 p0 = __builtin_amdgcn_permlane32_swap(t00.u, t10.u, false, false); \
            u32x2 e0 = __builtin_amdgcn_permlane16_swap(p0[0], p0[1], false, false); \
            u32x2 p1 = __builtin_amdgcn_permlane32_swap(t01.u, t11.u, false, false); \
            u32x2 e1 = __builtin_amdgcn_permlane16_swap(p1[0], p1[1], false, false); \
            union { unsigned int u[4]; bf16x8 h; } w;                           \
            w.u[0] = e0[0]; w.u[1] = e1[0]; w.u[2] = e0[1]; w.u[3] = e1[1];     \
            af[qs] = w.h;                                                       \
        }

    // ---- iter 0 (peeled): QK + exp/exchange + V0 frags; no PV yet ----
    {
        const bf16_t* Ks0 = (const bf16_t*)(smem + 16384);
        const bf16_t* Vs0 = (const bf16_t*)(smem + 32768);
        gload_lds16(Kg + base + (size_t)(64 + rk) * 1024 + gk,
                    (bf16_t*)(smem + 24576) + (wv * 64) * 8);
        gload_lds16(VTg + vbase + (size_t)rk * 2048 + 64 + gk,
                    (bf16_t*)(smem + 40960) + (wv * 64) * 8);

        f32x4 sa[2][2];   // [st][qs]
        for (int st = 0; st < 2; st++)
            for (int qs = 0; qs < 2; qs++) sa[st][qs] = (f32x4)0.0f;
        for (int st = 0; st < 2; st++) {
            const int srow = (sh * 32 + st * 16 + l16) * 64;
            bf16x8 kb0 = *(const bf16x8*)&Ks0[srow + fs0];
            bf16x8 kb1 = *(const bf16x8*)&Ks0[srow + fs1];
            for (int qs = 0; qs < 2; qs++) {
                sa[st][qs] = MFMA16(kb0, aq[qs][0], sa[st][qs]);
                sa[st][qs] = MFMA16(kb1, aq[qs][1], sa[st][qs]);
            }
        }
        EXCHANGE_P(sa)
        for (int nt = 0; nt < 4; nt++)
            bvf[nt] = *(const bf16x8*)&Vs0[(nt * 16 + l16) * 64 + fsA];
    }

    // ---- main loop kt = 1..31: QK(kt) + PV(kt-1); exchange(kt) -> af ----
#pragma unroll 2
    for (int kt = 1; kt < 32; kt++) {
        const int cur = kt & 1, prv = cur ^ 1;
        const bf16_t* KsC = (const bf16_t*)(smem + 16384 + cur * 8192);
        const bf16_t* VsC = (const bf16_t*)(smem + 32768 + cur * 8192);
        __syncthreads();   // K/V tile kt landed

        if (kt < 31) {
            gload_lds16(Kg + base + (size_t)((kt + 1) * 64 + rk) * 1024 + gk,
                        (bf16_t*)(smem + 16384 + prv * 8192) + (wv * 64) * 8);
            gload_lds16(VTg + vbase + (size_t)rk * 2048 + (kt + 1) * 64 + gk,
                        (bf16_t*)(smem + 32768 + prv * 8192) + (wv * 64) * 8);
        }

        // QK(kt): S^T chunk [32s x 32q]; each K-frag feeds both q-subtiles
        f32x4 sa[2][2];
        for (int st = 0; st < 2; st++)
            for (int qs = 0; qs < 2; qs++) sa[st][qs] = (f32x4)0.0f;
        __builtin_amdgcn_s_setprio(1);
        for (int st = 0; st < 2; st++) {
            const int srow = (sh * 32 + st * 16 + l16) * 64;
            bf16x8 kb0 = *(const bf16x8*)&KsC[srow + fs0];
            bf16x8 kb1 = *(const bf16x8*)&KsC[srow + fs1];
            for (int qs = 0; qs < 2; qs++) {
                sa[st][qs] = MFMA16(kb0, aq[qs][0], sa[st][qs]);
                sa[st][qs] = MFMA16(kb1, aq[qs][1], sa[st][qs]);
            }
        }

        // PV(kt-1): U += E1 @ V ; l1 += E1 @ ones  (s-partial, this sh only)
        l1acc[0] = MFMA16(af[0], ones, l1acc[0]);
        l1acc[1] = MFMA16(af[1], ones, l1acc[1]);
        for (int nt = 0; nt < 4; nt++) {
            oa[0][nt] = MFMA16(af[0], bvf[nt], oa[0][nt]);
            oa[1][nt] = MFMA16(af[1], bvf[nt], oa[1][nt]);
        }
        __builtin_amdgcn_s_setprio(0);

        // V(kt) frags for next iteration (Vs[cur] stable this iter)
        for (int nt = 0; nt < 4; nt++)
            bvf[nt] = *(const bf16x8*)&VsC[(nt * 16 + l16) * 64 + fsA];

        // exp2(kt) + quad-exchange -> af, under the PV MFMA drain
        EXCHANGE_P(sa)
    }

    // ---- drain: PV(31) from held af/bvf ----
    {
        l1acc[0] = MFMA16(af[0], ones, l1acc[0]);
        l1acc[1] = MFMA16(af[1], ones, l1acc[1]);
        for (int nt = 0; nt < 4; nt++) {
            oa[0][nt] = MFMA16(af[0], bvf[nt], oa[0][nt]);
            oa[1][nt] = MFMA16(af[1], bvf[nt], oa[1][nt]);
        }
    }

    // ---- pair-reduce (sh=1 -> sh=0) via LDS overlay, bank-swizzled ----
    __syncthreads();   // all iter-31 K/V reads done before overlay writes
    f32x4* R4 = (f32x4*)smem;                 // 2048 slots (32 KB) for oa
    f32x4* L4 = (f32x4*)(smem + 32768);       // 512 slots (8 KB) for l1
    const int bi = qg * 64 + lane;
    if (sh == 1) {
        for (int qs = 0; qs < 2; qs++)
            for (int nt = 0; nt < 4; nt++)
                R4[bi * 8 + ((qs * 4 + nt) ^ (lane & 7))] = oa[qs][nt];
        L4[bi * 2 + 0] = l1acc[0];
        L4[bi * 2 + 1] = l1acc[1];
    }
    __syncthreads();
    if (sh == 0) {
        for (int qs = 0; qs < 2; qs++)
            for (int nt = 0; nt < 4; nt++)
                oa[qs][nt] += R4[bi * 8 + ((qs * 4 + nt) ^ (lane & 7))];
        l1acc[0] += L4[bi * 2 + 0];
        l1acc[1] += L4[bi * 2 + 1];

        float invq[2][4];
        for (int qs = 0; qs < 2; qs++)
            for (int r = 0; r < 4; r++) invq[qs][r] = 1.0f / l1acc[qs][r];

        // Vsum[w] from Vpart: each quad sums 4 of the 16 partials, butterfly
        float vs[4];
        const size_t vprow = (size_t)(b * 16 + h) * 64;
        for (int nt = 0; nt < 4; nt++) {
            const f32x4 p4 = *(const f32x4*)&Vp[(vprow + nt * 16 + l16) * 16 + quad * 4];
            float t = (p4[0] + p4[1]) + (p4[2] + p4[3]);
            t += __shfl_xor(t, 16, 64);
            t += __shfl_xor(t, 32, 64);
            vs[nt] = t;
        }

        const float inv_denom = 1.0f / 2049.0f;
        for (int qs = 0; qs < 2; qs++)
            for (int nt = 0; nt < 4; nt++)
                for (int r = 0; r < 4; r++) {
                    const int srow = q0 + qg * 32 + qs * 16 + quad * 4 + r;
                    out[((size_t)b * 2048 + srow) * 1024 + (size_t)h * 64 + nt * 16 + l16] =
                        (vs[nt] + oa[qs][nt][r] * invq[qs][r]) * inv_denom;
                }
    }
    #undef EXCHANGE_P
}

// ---------------------------------------------------------------------------
extern "C" void kernel_launch(void* const* d_in, const int* in_sizes, int n_in,
                              void* d_out, int out_size, void* d_ws, size_t ws_size,
                              hipStream_t stream) {
    const float* x  = (const float*)d_in[0];
    const float* Wq = (const float*)d_in[1];
    const float* bq = (const float*)d_in[2];
    const float* Wk = (const float*)d_in[3];
    const float* bk = (const float*)d_in[4];
    const float* Wv = (const float*)d_in[5];
    const float* bv = (const float*)d_in[6];

    // Q/K/VT bf16 workspace (24 MB) + Vpart f32 partials (128 KB at +24 MB)
    bf16_t* Qw  = (bf16_t*)d_ws;
    bf16_t* Kw  = Qw + (size_t)4096 * 1024;
    bf16_t* VTw = Kw + (size_t)4096 * 1024;
    float*  Vp  = (float*)(VTw + (size_t)4096 * 1024);   // 2048 x 16 f32

    // bf16 input staging lives in d_out (16 MB; attn overwrites it last)
    bf16_t* xb  = (bf16_t*)d_out;
    bf16_t* Wqb = xb + (size_t)4096 * 1024;
    bf16_t* Wkb = Wqb + (size_t)1024 * 1024;
    bf16_t* Wvb = Wkb + (size_t)1024 * 1024;

    cvt_bf16<<<dim3(1024, 1, 4), 256, 0, stream>>>(x, Wq, Wk, Wv, xb, Wqb, Wkb, Wvb);
    qkv_gemm_bf16<<<dim3(32, 8, 3), 512, 0, stream>>>(
        xb, Wqb, bq, Wkb, bk, Wvb, bv, Qw, Kw, VTw, Vp);
    attn<<<dim3(16, 16, 2), 512, 0, stream>>>(Qw, Kw, VTw, Vp, (float*)d_out);
}